// Round 1
// baseline (494.166 us; speedup 1.0000x reference)
//
#include <hip/hip_runtime.h>

#define NB 4
#define CHN 512
#define HWD 4096
#define LTOT (NB*HWD)
#define FEAT_ 256
#define POOL_ 8192

typedef __attribute__((ext_vector_type(8))) __bf16 bf16x8;
typedef __attribute__((ext_vector_type(8))) unsigned short u16x8;
typedef __attribute__((ext_vector_type(4))) float f32x4;

static __device__ __forceinline__ unsigned short f2bf(float f){
  union { float f; unsigned u; } c; c.f = f;
  unsigned u = c.u;
  u += 0x7fffu + ((u >> 16) & 1u);   // round-to-nearest-even
  return (unsigned short)(u >> 16);
}

static __device__ __forceinline__ f32x4 mfma16(bf16x8 a, bf16x8 b, f32x4 c){
  return __builtin_amdgcn_mfma_f32_16x16x32_bf16(a, b, c, 0, 0, 0);
}

static __device__ __forceinline__ bf16x8 ld_bf8(const void* p){
  u16x8 v = *(const u16x8*)p;
  return __builtin_bit_cast(bf16x8, v);
}

static __device__ __forceinline__ void gload16(const void* g, void* l){
  __builtin_amdgcn_global_load_lds((const __attribute__((address_space(1))) void*)g,
                                   (__attribute__((address_space(3))) void*)l, 16, 0, 0);
}

// ---------------- f32 -> bf16 convert (layout-preserving) ----------------
__global__ void k_cvt(const float* __restrict__ src, unsigned short* __restrict__ dst, int n4){
  int i = blockIdx.x * 256 + threadIdx.x;
  if (i < n4) {
    const float4 v = *(const float4*)(src + (size_t)i * 4);
    ushort4 o; o.x = f2bf(v.x); o.y = f2bf(v.y); o.z = f2bf(v.z); o.w = f2bf(v.w);
    *(ushort4*)(dst + (size_t)i * 4) = o;
  }
}

// ---------------- pool [256][8192] f32 -> poolT_swz [8192][256] bf16 ----------------
// row p stored with byte_off(f) = (f*2) ^ ((p&7)<<4)
__global__ __launch_bounds__(256) void k_poolT(const float* __restrict__ pool,
                                               unsigned short* __restrict__ poolT){
  __shared__ float tile[32][33];
  int bf = blockIdx.x & 7;
  int bp = blockIdx.x >> 3;
  int t = threadIdx.x;
  int fi = t >> 3, j = (t & 7) * 4;
  const float4 v = *(const float4*)(pool + (size_t)(bf*32 + fi) * POOL_ + bp*32 + j);
  tile[fi][j+0] = v.x; tile[fi][j+1] = v.y; tile[fi][j+2] = v.z; tile[fi][j+3] = v.w;
  __syncthreads();
  int pi = t >> 3, fj = (t & 7) * 4;
  int p = bp*32 + pi;
  ushort4 o;
  o.x = f2bf(tile[fj+0][pi]); o.y = f2bf(tile[fj+1][pi]);
  o.z = f2bf(tile[fj+2][pi]); o.w = f2bf(tile[fj+3][pi]);
  int fbyte = (bf*32 + fj) * 2;
  char* dst = (char*)poolT + (size_t)p * 512 + (fbyte ^ ((p & 7) << 4));
  *(ushort4*)dst = o;
}

// ---------------- x [4][512][4096] f32 -> xT [4][4096][512] bf16 ----------------
__global__ __launch_bounds__(256) void k_xT(const float* __restrict__ x,
                                            unsigned short* __restrict__ xT){
  __shared__ float tile[32][33];
  int b = blockIdx.x;
  int lt = b & 127; int ct = (b >> 7) & 15; int n = b >> 11;
  int t = threadIdx.x;
  int fi = t >> 3, j = (t & 7) * 4;
  const float4 v = *(const float4*)(x + ((size_t)(n*CHN + ct*32 + fi)) * HWD + lt*32 + j);
  tile[fi][j+0] = v.x; tile[fi][j+1] = v.y; tile[fi][j+2] = v.z; tile[fi][j+3] = v.w;
  __syncthreads();
  int pi = t >> 3, fj = (t & 7) * 4;
  ushort4 o;
  o.x = f2bf(tile[fj+0][pi]); o.y = f2bf(tile[fj+1][pi]);
  o.z = f2bf(tile[fj+2][pi]); o.w = f2bf(tile[fj+3][pi]);
  *(ushort4*)((char*)xT + ((size_t)(n*HWD + lt*32 + pi)) * 1024 + (ct*32 + fj) * 2) = o;
}

// ---------------- theta GEMM: Q[l][f] = sum_c xT[l][c] * wt[f][c] ----------------
__global__ __launch_bounds__(256) void k_theta(const unsigned short* __restrict__ xT,
                                               const unsigned short* __restrict__ wt,
                                               unsigned short* __restrict__ Q){
  int w = threadIdx.x >> 6, lane = threadIdx.x & 63;
  int lq = lane & 15, hq = lane >> 4;
  int lbase = blockIdx.x * 64 + w * 16;
  const char* xb = (const char*)xT;
  const char* wb = (const char*)wt;
  f32x4 acc[16];
  #pragma unroll
  for (int i = 0; i < 16; ++i) acc[i] = {};
  #pragma unroll 2
  for (int kk = 0; kk < 16; ++kk) {
    bf16x8 a = ld_bf8(xb + (size_t)(lbase + lq) * 1024 + kk*64 + hq*16);
    #pragma unroll
    for (int fi = 0; fi < 16; ++fi) {
      bf16x8 bfr = ld_bf8(wb + (size_t)(fi*16 + lq) * 1024 + kk*64 + hq*16);
      acc[fi] = mfma16(a, bfr, acc[fi]);
    }
  }
  #pragma unroll
  for (int fi = 0; fi < 16; ++fi) {
    #pragma unroll
    for (int r = 0; r < 4; ++r) {
      int l = lbase + hq*4 + r;
      Q[(size_t)l * 256 + fi*16 + lq] = f2bf(acc[fi][r]);
    }
  }
}

// ---------------- fused flash attention over the concept pool ----------------
// Q [16384][256] bf16, K = poolT_swz [8192][256] bf16 (row-swizzled),
// V = poolN [256][8192] bf16 (natural). agg out: [16384][256] bf16.
__global__ __launch_bounds__(256, 3) void k_attn(const unsigned short* __restrict__ Qg,
                                                 const unsigned short* __restrict__ poolT,
                                                 const unsigned short* __restrict__ poolN,
                                                 unsigned short* __restrict__ agg){
  __shared__ unsigned short K_lds[32*256];     // 16 KB: [32 p][256 us] swizzled rows
  __shared__ unsigned short V_lds[256*40];     // 20 KB: [256 f][40 us] (80B padded rows)
  __shared__ unsigned short P_lds[4][16*40];   //  5 KB: per-wave [16 q][40 us]
  int w = threadIdx.x >> 6, lane = threadIdx.x & 63;
  int lq = lane & 15, hq = lane >> 4;
  int lbase = blockIdx.x * 64 + w * 16;
  const char* qb = (const char*)Qg;
  bf16x8 qf[8];
  #pragma unroll
  for (int kk = 0; kk < 8; ++kk)
    qf[kk] = ld_bf8(qb + (size_t)(lbase + lq) * 512 + kk*64 + hq*16);
  f32x4 acc[16];
  #pragma unroll
  for (int i = 0; i < 16; ++i) acc[i] = {};
  f32x4 accs = {};
  float m0 = -__builtin_inff(), m1 = -__builtin_inff(),
        m2 = -__builtin_inff(), m3 = -__builtin_inff();
  u16x8 ov;
  #pragma unroll
  for (int i = 0; i < 8; ++i) ov[i] = 0x3F80;   // bf16 1.0
  const bf16x8 ONES = __builtin_bit_cast(bf16x8, ov);

  const char* ktb = (const char*)poolT;
  const char* vnb = (const char*)poolN;
  int koff[4];
  #pragma unroll
  for (int i = 0; i < 4; ++i) koff[i] = (w*4 + i) * 1024;
  int vf[5], vrem[5];
  #pragma unroll
  for (int i = 0; i < 5; ++i) {
    int byb = (w*5 + i) * 1024 + lane * 16;
    vf[i] = byb / 80;
    int r = byb - vf[i] * 80;
    vrem[i] = (r < 64) ? r : 0;   // pad region -> harmless in-bounds read
  }
  int xorv = (lq & 7) << 3;   // ushort-index XOR = byte XOR ((p&7)<<4)

  for (int t = 0; t < 256; ++t) {
    __syncthreads();
    #pragma unroll
    for (int i = 0; i < 4; ++i)
      gload16(ktb + (size_t)t*16384 + koff[i] + lane*16, (char*)K_lds + koff[i]);
    #pragma unroll
    for (int i = 0; i < 5; ++i)
      gload16(vnb + (size_t)vf[i]*16384 + (size_t)t*64 + vrem[i],
              (char*)V_lds + (w*5 + i) * 1024);
    asm volatile("s_waitcnt vmcnt(0)" ::: "memory");
    __syncthreads();

    // S = Q @ K^T  -> 16 q rows x 32 p cols
    f32x4 s0 = {}, s1 = {};
    int rb0 = lq * 256;
    int rb1 = (16 + lq) * 256;
    #pragma unroll
    for (int kk = 0; kk < 8; ++kk) {
      int co = (kk*32 + hq*8) ^ xorv;
      bf16x8 k0 = ld_bf8(&K_lds[rb0 + co]);
      s0 = mfma16(qf[kk], k0, s0);
      bf16x8 k1 = ld_bf8(&K_lds[rb1 + co]);
      s1 = mfma16(qf[kk], k1, s1);
    }

    // online softmax: skip the lane-reduce + rescale when the max can't grow
    float p0 = fmaxf(s0[0], s1[0]), p1 = fmaxf(s0[1], s1[1]),
          p2 = fmaxf(s0[2], s1[2]), p3 = fmaxf(s0[3], s1[3]);
    bool ex = (p0 > m0) | (p1 > m1) | (p2 > m2) | (p3 > m3);
    if (__any((int)ex)) {
      #pragma unroll
      for (int msk = 1; msk < 16; msk <<= 1) {
        p0 = fmaxf(p0, __shfl_xor(p0, msk));
        p1 = fmaxf(p1, __shfl_xor(p1, msk));
        p2 = fmaxf(p2, __shfl_xor(p2, msk));
        p3 = fmaxf(p3, __shfl_xor(p3, msk));
      }
      float n0 = fmaxf(m0, p0), n1 = fmaxf(m1, p1),
            n2 = fmaxf(m2, p2), n3 = fmaxf(m3, p3);
      f32x4 sc;
      sc[0] = __expf(m0 - n0); sc[1] = __expf(m1 - n1);
      sc[2] = __expf(m2 - n2); sc[3] = __expf(m3 - n3);
      m0 = n0; m1 = n1; m2 = n2; m3 = n3;
      #pragma unroll
      for (int i = 0; i < 16; ++i) acc[i] *= sc;
      accs *= sc;
    }

    // P = exp(S - m), bf16, into this wave's padded P buffer
    {
      unsigned short* Pw = &P_lds[w][0];
      int q0 = hq * 4;
      Pw[(q0+0)*40 + lq]      = f2bf(__expf(s0[0] - m0));
      Pw[(q0+0)*40 + 16 + lq] = f2bf(__expf(s1[0] - m0));
      Pw[(q0+1)*40 + lq]      = f2bf(__expf(s0[1] - m1));
      Pw[(q0+1)*40 + 16 + lq] = f2bf(__expf(s1[1] - m1));
      Pw[(q0+2)*40 + lq]      = f2bf(__expf(s0[2] - m2));
      Pw[(q0+2)*40 + 16 + lq] = f2bf(__expf(s1[2] - m2));
      Pw[(q0+3)*40 + lq]      = f2bf(__expf(s0[3] - m3));
      Pw[(q0+3)*40 + 16 + lq] = f2bf(__expf(s1[3] - m3));
    }

    // PV: acc[q][f] += P[q][p] * V[p][f]; row-sum via ones-MFMA
    bf16x8 pa = ld_bf8(&P_lds[w][lq*40 + hq*8]);
    accs = mfma16(pa, ONES, accs);
    #pragma unroll
    for (int fi = 0; fi < 16; ++fi) {
      bf16x8 vfrag = ld_bf8(&V_lds[(fi*16 + lq)*40 + hq*8]);
      acc[fi] = mfma16(pa, vfrag, acc[fi]);
    }
  }

  #pragma unroll
  for (int fi = 0; fi < 16; ++fi) {
    #pragma unroll
    for (int r = 0; r < 4; ++r) {
      float v = acc[fi][r] / accs[r];
      agg[(size_t)(lbase + hq*4 + r) * 256 + fi*16 + lq] = f2bf(v);
    }
  }
}

// ---------------- output GEMM + gated residual ----------------
// out[n][c][l] = x[n][c][l] + gamma * sum_f wo[c][f] * agg[n*HW+l][f]
__global__ __launch_bounds__(256) void k_out(const float* __restrict__ x,
                                             const unsigned short* __restrict__ wo,
                                             const unsigned short* __restrict__ agg,
                                             const float* __restrict__ gammap,
                                             float* __restrict__ out){
  int w = threadIdx.x >> 6, lane = threadIdx.x & 63;
  int lq = lane & 15, hq = lane >> 4;
  int b = blockIdx.x;
  int lg = b & 63, cg = (b >> 6) & 7, n = b >> 9;
  const char* wb = (const char*)wo;
  const char* ab = (const char*)agg;
  f32x4 acc[4];
  #pragma unroll
  for (int i = 0; i < 4; ++i) acc[i] = {};
  int crow = cg*64 + w*16 + lq;
  #pragma unroll
  for (int kk = 0; kk < 8; ++kk) {
    bf16x8 a = ld_bf8(wb + (size_t)crow * 512 + kk*64 + hq*16);
    #pragma unroll
    for (int li = 0; li < 4; ++li) {
      bf16x8 bb = ld_bf8(ab + (size_t)(n*HWD + lg*64 + li*16 + lq) * 512 + kk*64 + hq*16);
      acc[li] = mfma16(a, bb, acc[li]);
    }
  }
  float g = gammap[0];
  #pragma unroll
  for (int li = 0; li < 4; ++li) {
    #pragma unroll
    for (int r = 0; r < 4; ++r) {
      int c = cg*64 + w*16 + hq*4 + r;
      int l = lg*64 + li*16 + lq;
      size_t idx = ((size_t)(n*CHN + c)) * HWD + l;
      out[idx] = x[idx] + g * acc[li][r];
    }
  }
}

extern "C" void kernel_launch(void* const* d_in, const int* in_sizes, int n_in,
                              void* d_out, int out_size, void* d_ws, size_t ws_size,
                              hipStream_t stream) {
  const float* x     = (const float*)d_in[0];
  const float* wt    = (const float*)d_in[1];
  const float* wo    = (const float*)d_in[2];
  const float* pool  = (const float*)d_in[3];
  const float* gamma = (const float*)d_in[4];
  char* ws = (char*)d_ws;
  unsigned short* wt_b  = (unsigned short*)(ws + 0);         // 256 KB
  unsigned short* wo_b  = (unsigned short*)(ws + 262144);    // 256 KB
  unsigned short* poolN = (unsigned short*)(ws + 524288);    // 4 MB
  unsigned short* poolT = (unsigned short*)(ws + 4718592);   // 4 MB
  unsigned short* xT    = (unsigned short*)(ws + 8912896);   // 16 MB
  unsigned short* Qb    = (unsigned short*)(ws + 25690112);  // 8 MB
  unsigned short* aggb  = (unsigned short*)(ws + 34078720);  // 8 MB
  float* out = (float*)d_out;

  k_cvt<<<dim3(128), dim3(256), 0, stream>>>(wt, wt_b, 32768);
  k_cvt<<<dim3(128), dim3(256), 0, stream>>>(wo, wo_b, 32768);
  k_cvt<<<dim3(2048), dim3(256), 0, stream>>>(pool, poolN, 524288);
  k_poolT<<<dim3(2048), dim3(256), 0, stream>>>(pool, poolT);
  k_xT<<<dim3(8192), dim3(256), 0, stream>>>(x, xT);
  k_theta<<<dim3(256), dim3(256), 0, stream>>>(xT, wt_b, Qb);
  k_attn<<<dim3(256), dim3(256), 0, stream>>>(Qb, poolT, poolN, aggb);
  k_out<<<dim3(2048), dim3(256), 0, stream>>>(x, wo_b, aggb, gamma, out);
}